// Round 4
// baseline (1357.423 us; speedup 1.0000x reference)
//
#include <hip/hip_runtime.h>
#include <math.h>

#define N_TOK 131072
#define DIM   64
#define QS    8
#define KS    1024
#define CHUNK 128              // codewords staged in LDS per iteration
#define TTILE 2                // 16-token register tiles per wave

typedef _Float16 f16x8 __attribute__((ext_vector_type(8)));
typedef float    f32x4 __attribute__((ext_vector_type(4)));

#define AS1C(p) ((const __attribute__((address_space(1))) void*)(p))
#define AS3(p)  ((__attribute__((address_space(3))) void*)(p))

// ---- pre-pass 1: split fp32 codebook into two f16 limbs (lo limb scaled by 2^11) ----
__global__ void conv_kernel(const float* __restrict__ cb,
                            _Float16* __restrict__ ch, _Float16* __restrict__ cl) {
    int i = blockIdx.x * blockDim.x + threadIdx.x;
    if (i < QS * KS * DIM) {
        float c = cb[i];
        _Float16 hi = (_Float16)c;
        ch[i] = hi;
        cl[i] = (_Float16)((c - (float)hi) * 2048.0f);   // scaled: stays in normal f16 range
    }
}

// ---- pre-pass 2: -0.5 * ||c||^2 (exact fp32), injected via MFMA C-operand ----
__global__ void dc2_kernel(const float* __restrict__ cb, float* __restrict__ dc2h) {
    int i = blockIdx.x * blockDim.x + threadIdx.x;
    if (i < QS * KS) {
        const float* c = cb + (size_t)i * DIM;
        float s = 0.f;
#pragma unroll
        for (int d = 0; d < DIM; ++d) s = fmaf(c[d], c[d], s);
        dc2h[i] = -0.5f * s;
    }
}

// ---- main: 4 waves/block, TWO 16-token tiles per wave ----
// argmax of  val = r.c - 0.5*||c||^2   (== argmin of squared distance)
__global__ __launch_bounds__(256, 3)
void rvq_mfma_kernel(const float* __restrict__ x,
                     const float* __restrict__ cbf,
                     const _Float16* __restrict__ chg,
                     const _Float16* __restrict__ clg,
                     const float* __restrict__ dc2h,
                     float* __restrict__ out) {
    __shared__ _Float16 lbuf[CHUNK / 16][2][2][64][8];   // 32 KB codebook chunk
    __shared__ float    ldc2[CHUNK];                      // -||c||^2/2 chunk
    __shared__ int      idxLDS[4][32];

    const int tid  = threadIdx.x;
    const int wave = tid >> 6;
    const int lane = tid & 63;
    const int quad = lane >> 4;      // A frag: k-group; C/D: row-group
    const int m    = lane & 15;      // A frag: token row; B frag / C-D col: codeword

    const int tokenBase = blockIdx.x * (64 * TTILE) + wave * (16 * TTILE);

    // residual, A-frag layout per tile: r[t][j] = R[tok][quad*8+j], r[t][8+j] = R[tok][32+quad*8+j]
    float r[TTILE][16];
#pragma unroll
    for (int t = 0; t < TTILE; ++t) {
        const float* xp = x + (size_t)(tokenBase + t * 16 + m) * DIM + quad * 8;
        f32x4 a0 = __builtin_nontemporal_load((const f32x4*)(xp));
        f32x4 a1 = __builtin_nontemporal_load((const f32x4*)(xp + 4));
        f32x4 a2 = __builtin_nontemporal_load((const f32x4*)(xp + 32));
        f32x4 a3 = __builtin_nontemporal_load((const f32x4*)(xp + 36));
#pragma unroll
        for (int i = 0; i < 4; ++i) {
            r[t][i] = a0[i]; r[t][4+i] = a1[i]; r[t][8+i] = a2[i]; r[t][12+i] = a3[i];
        }
    }

    int idxAcc[TTILE][QS];

    for (int q = 0; q < QS; ++q) {
        const _Float16* chq = chg  + (size_t)q * KS * DIM;
        const _Float16* clq = clg  + (size_t)q * KS * DIM;
        const float*    dq  = dc2h + q * KS;
        const float*    cfq = cbf  + (size_t)q * KS * DIM;

        // split residual into f16 limbs (A-frags)
        f16x8 ah[TTILE][2], al[TTILE][2];
#pragma unroll
        for (int t = 0; t < TTILE; ++t)
#pragma unroll
            for (int j = 0; j < 8; ++j) {
                float v0 = r[t][j], v1 = r[t][8 + j];
                _Float16 h0 = (_Float16)v0, h1 = (_Float16)v1;
                ah[t][0][j] = h0;  ah[t][1][j] = h1;
                al[t][0][j] = (_Float16)((v0 - (float)h0) * 2048.0f);
                al[t][1][j] = (_Float16)((v1 - (float)h1) * 2048.0f);
            }

        float bestv[TTILE][4];
        int   besti[TTILE][4];
#pragma unroll
        for (int t = 0; t < TTILE; ++t)
#pragma unroll
            for (int i = 0; i < 4; ++i) { bestv[t][i] = -INFINITY; besti[t][i] = 0; }

        for (int k0 = 0; k0 < KS; k0 += CHUNK) {
            __syncthreads();                      // prior chunk's LDS reads done
#pragma unroll
            for (int t2 = 0; t2 < 2; ++t2) {      // async stage: 8x 1KB per wave
                const int nn  = wave * 2 + t2;
                const size_t goff = (size_t)(k0 + nn * 16 + m) * DIM + quad * 8;
#pragma unroll
                for (int half = 0; half < 2; ++half) {
                    __builtin_amdgcn_global_load_lds(AS1C(chq + goff + half * 32),
                        AS3(&lbuf[nn][half][0][0][0]), 16, 0, 0);
                    __builtin_amdgcn_global_load_lds(AS1C(clq + goff + half * 32),
                        AS3(&lbuf[nn][half][1][0][0]), 16, 0, 0);
                }
            }
            if (tid < CHUNK) ldc2[tid] = dq[k0 + tid];
            __syncthreads();                      // drains vmcnt + lgkm

#pragma unroll
            for (int nn = 0; nn < CHUNK / 16; ++nn) {
                f16x8 bh0 = *(const f16x8*)&lbuf[nn][0][0][lane][0];
                f16x8 bh1 = *(const f16x8*)&lbuf[nn][1][0][lane][0];
                f16x8 bl0 = *(const f16x8*)&lbuf[nn][0][1][lane][0];
                f16x8 bl1 = *(const f16x8*)&lbuf[nn][1][1][lane][0];
                const float mdv = ldc2[nn * 16 + m];      // -||c||^2/2, this lane's col
                const int  cidx = k0 + nn * 16 + m;
                const f32x4 ci = {mdv, mdv, mdv, mdv};
                const f32x4 zero = {0.f, 0.f, 0.f, 0.f};

                f32x4 hh[TTILE], tx[TTILE];
#pragma unroll
                for (int t = 0; t < TTILE; ++t) {
                    hh[t] = __builtin_amdgcn_mfma_f32_16x16x32_f16(ah[t][0], bh0, ci, 0, 0, 0);
                    tx[t] = __builtin_amdgcn_mfma_f32_16x16x32_f16(ah[t][0], bl0, zero, 0, 0, 0);
                }
#pragma unroll
                for (int t = 0; t < TTILE; ++t) {
                    hh[t] = __builtin_amdgcn_mfma_f32_16x16x32_f16(ah[t][1], bh1, hh[t], 0, 0, 0);
                    tx[t] = __builtin_amdgcn_mfma_f32_16x16x32_f16(ah[t][1], bl1, tx[t], 0, 0, 0);
                }
#pragma unroll
                for (int t = 0; t < TTILE; ++t) {
                    tx[t] = __builtin_amdgcn_mfma_f32_16x16x32_f16(al[t][0], bh0, tx[t], 0, 0, 0);
                    tx[t] = __builtin_amdgcn_mfma_f32_16x16x32_f16(al[t][1], bh1, tx[t], 0, 0, 0);
                }
#pragma unroll
                for (int t = 0; t < TTILE; ++t)
#pragma unroll
                    for (int i = 0; i < 4; ++i) {
                        // val = r.c - ||c||^2/2   (cross terms scaled back by 2^-11)
                        float v = fmaf(4.8828125e-4f, tx[t][i], hh[t][i]);
                        if (v > bestv[t][i]) { bestv[t][i] = v; besti[t][i] = cidx; }
                    }
            }
        }

        // cross-lane argmax over 16 cols (tie-break: lowest index == jnp.argmin semantics)
#pragma unroll
        for (int mask = 1; mask <= 8; mask <<= 1) {
#pragma unroll
            for (int t = 0; t < TTILE; ++t)
#pragma unroll
                for (int i = 0; i < 4; ++i) {
                    float ov = __shfl_xor(bestv[t][i], mask, 64);
                    int   oi = __shfl_xor(besti[t][i], mask, 64);
                    if (ov > bestv[t][i] || (ov == bestv[t][i] && oi < besti[t][i])) {
                        bestv[t][i] = ov; besti[t][i] = oi;
                    }
                }
        }

        if (m == 0) {
#pragma unroll
            for (int t = 0; t < TTILE; ++t)
#pragma unroll
                for (int i = 0; i < 4; ++i) idxLDS[wave][t * 16 + quad * 4 + i] = besti[t][i];
        }
        __syncthreads();

        // residual update: exact fp32 gather of chosen codeword (matches reference)
        float ls = 0.f;
#pragma unroll
        for (int t = 0; t < TTILE; ++t) {
            const int id = idxLDS[wave][t * 16 + m];
            idxAcc[t][q] = id;
            const float* cp = cfq + (size_t)id * DIM + quad * 8;
            f32x4 c0 = *(const f32x4*)(cp);
            f32x4 c1 = *(const f32x4*)(cp + 4);
            f32x4 c2 = *(const f32x4*)(cp + 32);
            f32x4 c3 = *(const f32x4*)(cp + 36);
#pragma unroll
            for (int i = 0; i < 4; ++i) {
                r[t][i]    -= c0[i];  r[t][4+i]  -= c1[i];
                r[t][8+i]  -= c2[i];  r[t][12+i] -= c3[i];
            }
#pragma unroll
            for (int j = 0; j < 16; ++j) ls = fmaf(r[t][j], r[t][j], ls);
        }
#pragma unroll
        for (int mask = 1; mask <= 32; mask <<= 1) ls += __shfl_xor(ls, mask, 64);
        if (lane == 0)
            atomicAdd(out + (size_t)N_TOK * DIM + (size_t)N_TOK * QS + q,
                      ls * (1.0f / ((float)N_TOK * (float)DIM)));
    }

    // xq = x - r_final   (streaming)
#pragma unroll
    for (int t = 0; t < TTILE; ++t) {
        const size_t rowoff = (size_t)(tokenBase + t * 16 + m) * DIM + quad * 8;
        const float* xp = x + rowoff;
        float*       op = out + rowoff;
        f32x4 a0 = __builtin_nontemporal_load((const f32x4*)(xp));
        f32x4 a1 = __builtin_nontemporal_load((const f32x4*)(xp + 4));
        f32x4 a2 = __builtin_nontemporal_load((const f32x4*)(xp + 32));
        f32x4 a3 = __builtin_nontemporal_load((const f32x4*)(xp + 36));
        f32x4 o0, o1, o2, o3;
#pragma unroll
        for (int i = 0; i < 4; ++i) {
            o0[i] = a0[i] - r[t][i];     o1[i] = a1[i] - r[t][4+i];
            o2[i] = a2[i] - r[t][8+i];   o3[i] = a3[i] - r[t][12+i];
        }
        __builtin_nontemporal_store(o0, (f32x4*)(op));
        __builtin_nontemporal_store(o1, (f32x4*)(op + 4));
        __builtin_nontemporal_store(o2, (f32x4*)(op + 32));
        __builtin_nontemporal_store(o3, (f32x4*)(op + 36));
    }

    // indices: quad t writes tile t's tokens (coalesced 32B per token)
    if (quad < TTILE) {
        const int t = quad;
        float* idxp = out + (size_t)N_TOK * DIM + (size_t)(tokenBase + t * 16 + m) * QS;
        f32x4 i0, i1;
#pragma unroll
        for (int i = 0; i < 4; ++i) { i0[i] = (float)idxAcc[t][i]; i1[i] = (float)idxAcc[t][4+i]; }
        __builtin_nontemporal_store(i0, (f32x4*)(idxp));
        __builtin_nontemporal_store(i1, (f32x4*)(idxp + 4));
    }
}

extern "C" void kernel_launch(void* const* d_in, const int* in_sizes, int n_in,
                              void* d_out, int out_size, void* d_ws, size_t ws_size,
                              hipStream_t stream) {
    const float* x   = (const float*)d_in[0];   // (N, D)
    const float* cb  = (const float*)d_in[1];   // (Q, K, D)
    float*       out = (float*)d_out;           // [xq | indices | losses]
    char*        ws  = (char*)d_ws;

    _Float16* ch   = (_Float16*)ws;                       // 1 MB
    _Float16* cl   = (_Float16*)(ws + 1048576);           // 1 MB
    float*    dc2h = (float*)(ws + 2097152);              // 32 KB

    hipMemsetAsync(out + (size_t)N_TOK * DIM + (size_t)N_TOK * QS, 0,
                   QS * sizeof(float), stream);

    conv_kernel<<<(QS * KS * DIM + 255) / 256, 256, 0, stream>>>(cb, ch, cl);
    dc2_kernel<<<(QS * KS + 255) / 256, 256, 0, stream>>>(cb, dc2h);
    rvq_mfma_kernel<<<N_TOK / (64 * TTILE), 256, 0, stream>>>(x, cb, ch, cl, dc2h, out);
}

// Round 5
// 593.719 us; speedup vs baseline: 2.2863x; 2.2863x over previous
//
#include <hip/hip_runtime.h>
#include <math.h>

#define N_TOK 131072
#define DIM   64
#define QS    8
#define KS    1024
#define CHUNK 128              // codewords staged in LDS per iteration

typedef _Float16 f16x8 __attribute__((ext_vector_type(8)));
typedef float    f32x4 __attribute__((ext_vector_type(4)));

#define AS1C(p) ((const __attribute__((address_space(1))) void*)(p))
#define AS3(p)  ((__attribute__((address_space(3))) void*)(p))

#define RSCALE   2048.0f
#define RISCALE  4.8828125e-4f   // 2^-11

// split fp32 v into f16 limbs: v ~= hi + lo * 2^-11
#define SPLIT(v, hi, lo) { _Float16 _h = (_Float16)(v); (hi) = _h; \
                           (lo) = (_Float16)(((v) - (float)_h) * RSCALE); }

// ---- pre-pass 1: split fp32 codebook into two f16 limbs ----
__global__ void conv_kernel(const float* __restrict__ cb,
                            _Float16* __restrict__ ch, _Float16* __restrict__ cl) {
    int i = blockIdx.x * blockDim.x + threadIdx.x;
    if (i < QS * KS * DIM) {
        float c = cb[i];
        _Float16 hi = (_Float16)c;
        ch[i] = hi;
        cl[i] = (_Float16)((c - (float)hi) * RSCALE);
    }
}

// ---- pre-pass 2: -0.5 * ||c||^2 (exact fp32), injected via MFMA C-operand ----
__global__ void dc2_kernel(const float* __restrict__ cb, float* __restrict__ dc2h) {
    int i = blockIdx.x * blockDim.x + threadIdx.x;
    if (i < QS * KS) {
        const float* c = cb + (size_t)i * DIM;
        float s = 0.f;
#pragma unroll
        for (int d = 0; d < DIM; ++d) s = fmaf(c[d], c[d], s);
        dc2h[i] = -0.5f * s;
    }
}

// ---- main: 4 waves/block, 2 token-tiles (A,B) per wave, residual AS LIMBS ----
// argmax of  val = r.c - 0.5*||c||^2   (== argmin of squared distance)
__global__ __launch_bounds__(256, 4)
void rvq_mfma_kernel(const float* __restrict__ x,
                     const float* __restrict__ cbf,
                     const _Float16* __restrict__ chg,
                     const _Float16* __restrict__ clg,
                     const float* __restrict__ dc2h,
                     float* __restrict__ out) {
    __shared__ _Float16 lbuf[CHUNK / 16][2][2][64][8];   // 32 KB [nn][half][limb][lane][8]
    __shared__ float    ldc2[CHUNK];                      // 512 B
    __shared__ int      idxLDS[4][32];                    // 512 B

    const int tid  = threadIdx.x;
    const int wave = tid >> 6;
    const int lane = tid & 63;
    const int quad = lane >> 4;      // A frag: k-group; C/D: row-group
    const int m    = lane & 15;      // A frag: token row; B frag / C-D col: codeword

    const int tokenBase = blockIdx.x * 128 + wave * 32;   // tiles A,B of 16 tokens

    // residual limbs, A-frag layout: limb frag 0 -> dims quad*8+0..7, frag 1 -> dims 32+quad*8+0..7
    f16x8 ahA0, ahA1, alA0, alA1, ahB0, ahB1, alB0, alB1;
    {
        const float* xa = x + (size_t)(tokenBase + m) * DIM + quad * 8;
        const float* xb = x + (size_t)(tokenBase + 16 + m) * DIM + quad * 8;
        f32x4 a0 = __builtin_nontemporal_load((const f32x4*)(xa));
        f32x4 a1 = __builtin_nontemporal_load((const f32x4*)(xa + 4));
        f32x4 a2 = __builtin_nontemporal_load((const f32x4*)(xa + 32));
        f32x4 a3 = __builtin_nontemporal_load((const f32x4*)(xa + 36));
        f32x4 b0 = __builtin_nontemporal_load((const f32x4*)(xb));
        f32x4 b1 = __builtin_nontemporal_load((const f32x4*)(xb + 4));
        f32x4 b2 = __builtin_nontemporal_load((const f32x4*)(xb + 32));
        f32x4 b3 = __builtin_nontemporal_load((const f32x4*)(xb + 36));
#pragma unroll
        for (int j = 0; j < 4; ++j) {
            SPLIT(a0[j], ahA0[j],   alA0[j]);   SPLIT(a1[j], ahA0[j+4], alA0[j+4]);
            SPLIT(a2[j], ahA1[j],   alA1[j]);   SPLIT(a3[j], ahA1[j+4], alA1[j+4]);
            SPLIT(b0[j], ahB0[j],   alB0[j]);   SPLIT(b1[j], ahB0[j+4], alB0[j+4]);
            SPLIT(b2[j], ahB1[j],   alB1[j]);   SPLIT(b3[j], ahB1[j+4], alB1[j+4]);
        }
    }

    for (int q = 0; q < QS; ++q) {
        const _Float16* chq = chg  + (size_t)q * KS * DIM;
        const _Float16* clq = clg  + (size_t)q * KS * DIM;
        const float*    dq  = dc2h + q * KS;
        const float*    cfq = cbf  + (size_t)q * KS * DIM;

        float bvA[4], bvB[4];
        int   biA[4], biB[4];
#pragma unroll
        for (int i = 0; i < 4; ++i) {
            bvA[i] = -INFINITY; bvB[i] = -INFINITY; biA[i] = 0; biB[i] = 0;
        }

        for (int k0 = 0; k0 < KS; k0 += CHUNK) {
            __syncthreads();                      // prior chunk's LDS reads done
#pragma unroll
            for (int t2 = 0; t2 < 2; ++t2) {      // async stage: 8x 1KB per wave
                const int nn  = wave * 2 + t2;
                const size_t goff = (size_t)(k0 + nn * 16 + m) * DIM + quad * 8;
#pragma unroll
                for (int half = 0; half < 2; ++half) {
                    __builtin_amdgcn_global_load_lds(AS1C(chq + goff + half * 32),
                        AS3(&lbuf[nn][half][0][0][0]), 16, 0, 0);
                    __builtin_amdgcn_global_load_lds(AS1C(clq + goff + half * 32),
                        AS3(&lbuf[nn][half][1][0][0]), 16, 0, 0);
                }
            }
            if (tid < CHUNK) ldc2[tid] = dq[k0 + tid];
            __syncthreads();                      // drains vmcnt + lgkm

#pragma unroll 2
            for (int nn = 0; nn < CHUNK / 16; ++nn) {
                f16x8 bh0 = *(const f16x8*)&lbuf[nn][0][0][lane][0];
                f16x8 bh1 = *(const f16x8*)&lbuf[nn][1][0][lane][0];
                f16x8 bl0 = *(const f16x8*)&lbuf[nn][0][1][lane][0];
                f16x8 bl1 = *(const f16x8*)&lbuf[nn][1][1][lane][0];
                const float mdv = ldc2[nn * 16 + m];      // -||c||^2/2, this lane's col
                const int  cidx = k0 + nn * 16 + m;
                const f32x4 ci   = {mdv, mdv, mdv, mdv};
                const f32x4 zero = {0.f, 0.f, 0.f, 0.f};

                f32x4 hhA = __builtin_amdgcn_mfma_f32_16x16x32_f16(ahA0, bh0, ci, 0, 0, 0);
                f32x4 hhB = __builtin_amdgcn_mfma_f32_16x16x32_f16(ahB0, bh0, ci, 0, 0, 0);
                f32x4 txA = __builtin_amdgcn_mfma_f32_16x16x32_f16(alA0, bh0, zero, 0, 0, 0);
                f32x4 txB = __builtin_amdgcn_mfma_f32_16x16x32_f16(alB0, bh0, zero, 0, 0, 0);
                hhA = __builtin_amdgcn_mfma_f32_16x16x32_f16(ahA1, bh1, hhA, 0, 0, 0);
                hhB = __builtin_amdgcn_mfma_f32_16x16x32_f16(ahB1, bh1, hhB, 0, 0, 0);
                txA = __builtin_amdgcn_mfma_f32_16x16x32_f16(alA1, bh1, txA, 0, 0, 0);
                txB = __builtin_amdgcn_mfma_f32_16x16x32_f16(alB1, bh1, txB, 0, 0, 0);
                txA = __builtin_amdgcn_mfma_f32_16x16x32_f16(ahA0, bl0, txA, 0, 0, 0);
                txB = __builtin_amdgcn_mfma_f32_16x16x32_f16(ahB0, bl0, txB, 0, 0, 0);
                txA = __builtin_amdgcn_mfma_f32_16x16x32_f16(ahA1, bl1, txA, 0, 0, 0);
                txB = __builtin_amdgcn_mfma_f32_16x16x32_f16(ahB1, bl1, txB, 0, 0, 0);
#pragma unroll
                for (int i = 0; i < 4; ++i) {
                    float vA = fmaf(RISCALE, txA[i], hhA[i]);
                    float vB = fmaf(RISCALE, txB[i], hhB[i]);
                    if (vA > bvA[i]) { bvA[i] = vA; biA[i] = cidx; }
                    if (vB > bvB[i]) { bvB[i] = vB; biB[i] = cidx; }
                }
            }
        }

        // cross-lane argmax over 16 cols (tie-break: lowest index == argmin semantics)
#pragma unroll
        for (int mask = 1; mask <= 8; mask <<= 1) {
#pragma unroll
            for (int i = 0; i < 4; ++i) {
                float ovA = __shfl_xor(bvA[i], mask, 64);
                int   oiA = __shfl_xor(biA[i], mask, 64);
                if (ovA > bvA[i] || (ovA == bvA[i] && oiA < biA[i])) { bvA[i] = ovA; biA[i] = oiA; }
                float ovB = __shfl_xor(bvB[i], mask, 64);
                int   oiB = __shfl_xor(biB[i], mask, 64);
                if (ovB > bvB[i] || (ovB == bvB[i] && oiB < biB[i])) { bvB[i] = ovB; biB[i] = oiB; }
            }
        }

        // writer lanes: indices straight to global (no per-thread accumulation array)
        if (m == 0) {
            float* idxq = out + (size_t)N_TOK * DIM + q;
#pragma unroll
            for (int i = 0; i < 4; ++i) {
                const int rowA = quad * 4 + i;
                idxq[(size_t)(tokenBase + rowA) * QS]      = (float)biA[i];
                idxq[(size_t)(tokenBase + 16 + rowA) * QS] = (float)biB[i];
                idxLDS[wave][rowA]      = biA[i];
                idxLDS[wave][16 + rowA] = biB[i];
            }
        }
        __syncthreads();

        const int idA = idxLDS[wave][m];
        const int idB = idxLDS[wave][16 + m];

        // residual update: reconstruct r from limbs, subtract fp32 codeword, re-split
        float ls = 0.f;
        {
            const float* cp = cfq + (size_t)idA * DIM + quad * 8;
            f32x4 c0 = *(const f32x4*)(cp);
            f32x4 c1 = *(const f32x4*)(cp + 4);
            f32x4 c2 = *(const f32x4*)(cp + 32);
            f32x4 c3 = *(const f32x4*)(cp + 36);
#pragma unroll
            for (int j = 0; j < 4; ++j) {
                float v0 = fmaf(RISCALE, (float)alA0[j],   (float)ahA0[j])   - c0[j];
                float v1 = fmaf(RISCALE, (float)alA0[j+4], (float)ahA0[j+4]) - c1[j];
                float v2 = fmaf(RISCALE, (float)alA1[j],   (float)ahA1[j])   - c2[j];
                float v3 = fmaf(RISCALE, (float)alA1[j+4], (float)ahA1[j+4]) - c3[j];
                ls = fmaf(v0, v0, ls); ls = fmaf(v1, v1, ls);
                ls = fmaf(v2, v2, ls); ls = fmaf(v3, v3, ls);
                SPLIT(v0, ahA0[j],   alA0[j]);   SPLIT(v1, ahA0[j+4], alA0[j+4]);
                SPLIT(v2, ahA1[j],   alA1[j]);   SPLIT(v3, ahA1[j+4], alA1[j+4]);
            }
        }
        {
            const float* cp = cfq + (size_t)idB * DIM + quad * 8;
            f32x4 c0 = *(const f32x4*)(cp);
            f32x4 c1 = *(const f32x4*)(cp + 4);
            f32x4 c2 = *(const f32x4*)(cp + 32);
            f32x4 c3 = *(const f32x4*)(cp + 36);
#pragma unroll
            for (int j = 0; j < 4; ++j) {
                float v0 = fmaf(RISCALE, (float)alB0[j],   (float)ahB0[j])   - c0[j];
                float v1 = fmaf(RISCALE, (float)alB0[j+4], (float)ahB0[j+4]) - c1[j];
                float v2 = fmaf(RISCALE, (float)alB1[j],   (float)ahB1[j])   - c2[j];
                float v3 = fmaf(RISCALE, (float)alB1[j+4], (float)ahB1[j+4]) - c3[j];
                ls = fmaf(v0, v0, ls); ls = fmaf(v1, v1, ls);
                ls = fmaf(v2, v2, ls); ls = fmaf(v3, v3, ls);
                SPLIT(v0, ahB0[j],   alB0[j]);   SPLIT(v1, ahB0[j+4], alB0[j+4]);
                SPLIT(v2, ahB1[j],   alB1[j]);   SPLIT(v3, ahB1[j+4], alB1[j+4]);
            }
        }
#pragma unroll
        for (int mask = 1; mask <= 32; mask <<= 1) ls += __shfl_xor(ls, mask, 64);
        if (lane == 0)
            atomicAdd(out + (size_t)N_TOK * DIM + (size_t)N_TOK * QS + q,
                      ls * (1.0f / ((float)N_TOK * (float)DIM)));
    }

    // xq = x - r_final (reconstruct final residual from limbs)
    {
        const size_t ra = (size_t)(tokenBase + m) * DIM + quad * 8;
        const size_t rb = (size_t)(tokenBase + 16 + m) * DIM + quad * 8;
        f32x4 a0 = __builtin_nontemporal_load((const f32x4*)(x + ra));
        f32x4 a1 = __builtin_nontemporal_load((const f32x4*)(x + ra + 4));
        f32x4 a2 = __builtin_nontemporal_load((const f32x4*)(x + ra + 32));
        f32x4 a3 = __builtin_nontemporal_load((const f32x4*)(x + ra + 36));
        f32x4 b0 = __builtin_nontemporal_load((const f32x4*)(x + rb));
        f32x4 b1 = __builtin_nontemporal_load((const f32x4*)(x + rb + 4));
        f32x4 b2 = __builtin_nontemporal_load((const f32x4*)(x + rb + 32));
        f32x4 b3 = __builtin_nontemporal_load((const f32x4*)(x + rb + 36));
#pragma unroll
        for (int j = 0; j < 4; ++j) {
            a0[j] -= fmaf(RISCALE, (float)alA0[j],   (float)ahA0[j]);
            a1[j] -= fmaf(RISCALE, (float)alA0[j+4], (float)ahA0[j+4]);
            a2[j] -= fmaf(RISCALE, (float)alA1[j],   (float)ahA1[j]);
            a3[j] -= fmaf(RISCALE, (float)alA1[j+4], (float)ahA1[j+4]);
            b0[j] -= fmaf(RISCALE, (float)alB0[j],   (float)ahB0[j]);
            b1[j] -= fmaf(RISCALE, (float)alB0[j+4], (float)ahB0[j+4]);
            b2[j] -= fmaf(RISCALE, (float)alB1[j],   (float)ahB1[j]);
            b3[j] -= fmaf(RISCALE, (float)alB1[j+4], (float)ahB1[j+4]);
        }
        __builtin_nontemporal_store(a0, (f32x4*)(out + ra));
        __builtin_nontemporal_store(a1, (f32x4*)(out + ra + 4));
        __builtin_nontemporal_store(a2, (f32x4*)(out + ra + 32));
        __builtin_nontemporal_store(a3, (f32x4*)(out + ra + 36));
        __builtin_nontemporal_store(b0, (f32x4*)(out + rb));
        __builtin_nontemporal_store(b1, (f32x4*)(out + rb + 4));
        __builtin_nontemporal_store(b2, (f32x4*)(out + rb + 32));
        __builtin_nontemporal_store(b3, (f32x4*)(out + rb + 36));
    }
}

extern "C" void kernel_launch(void* const* d_in, const int* in_sizes, int n_in,
                              void* d_out, int out_size, void* d_ws, size_t ws_size,
                              hipStream_t stream) {
    const float* x   = (const float*)d_in[0];   // (N, D)
    const float* cb  = (const float*)d_in[1];   // (Q, K, D)
    float*       out = (float*)d_out;           // [xq | indices | losses]
    char*        ws  = (char*)d_ws;

    _Float16* ch   = (_Float16*)ws;                       // 1 MB
    _Float16* cl   = (_Float16*)(ws + 1048576);           // 1 MB
    float*    dc2h = (float*)(ws + 2097152);              // 32 KB

    hipMemsetAsync(out + (size_t)N_TOK * DIM + (size_t)N_TOK * QS, 0,
                   QS * sizeof(float), stream);

    conv_kernel<<<(QS * KS * DIM + 255) / 256, 256, 0, stream>>>(cb, ch, cl);
    dc2_kernel<<<(QS * KS + 255) / 256, 256, 0, stream>>>(cb, dc2h);
    rvq_mfma_kernel<<<N_TOK / 128, 256, 0, stream>>>(x, cb, ch, cl, dc2h, out);
}